// Round 3
// baseline (294.617 us; speedup 1.0000x reference)
//
#include <hip/hip_runtime.h>
#include <stdint.h>

// R13: attack the schedule-invariant bottleneck (R10/R11/R12 all 46-48us despite three
// different K-loop schedules). Two shared culprits targeted:
//   (a) L2 thrash: per-XCD working set was 5MB > 4MB L2 (FETCH 22.6MB vs 12.3MB
//       compulsory). Fix: 2D slab swizzle -> each XCD owns 8 mt x 16 nt
//       (A 2MB + B 2MB = 4MB, L2-resident).
//   (b) thin TLP + coarse tail: all variants had 8 waves/CU (2/SIMD), occupancy 17-18.5%
//       vs 25% structural. Fix: BM256xBN128, BK=64, 4-wave blocks, 48KB LDS ->
//       3 blocks/CU = 12 waves (3/SIMD), grid 1024 (4 fine rounds/CU).
// Schedule itself: simple proven 2-barrier loop with counted vmcnt(6) ring-2 (R11-style).
// Integer accumulation exact under reorder -> outputs bit-identical to R10/R11/R12.
// prep_k / resolve_k / finalize_k unchanged.

#define B_DIM 8192
#define D_DIM 1024
#define N_DIM 4096
#define ND ((size_t)N_DIM * D_DIM)
#define LRc 0.02f
#define ATc 0.3f
#define EMAc (0.02f * 0.1f)   // LR*DSBETA = 0.002
#define QS 32.0f              // i8 quant scale
#define INV_QS2 (1.0f / (QS * QS))
#define MARGIN_G 10.0f        // candidate window in g-units

typedef int intv4 __attribute__((ext_vector_type(4)));

__device__ __forceinline__ void async16(void* lds, const void* g) {
    __builtin_amdgcn_global_load_lds((const __attribute__((address_space(1))) void*)g,
                                     (__attribute__((address_space(3))) void*)lds, 16, 0, 0);
}

__device__ __forceinline__ int q8(float v) {
    return (int)rintf(fminf(fmaxf(v * QS, -127.0f), 127.0f));
}

__device__ __forceinline__ unsigned pack4(float4 v) {
    return (unsigned)(q8(v.x) & 255) | ((unsigned)(q8(v.y) & 255) << 8)
         | ((unsigned)(q8(v.z) & 255) << 16) | ((unsigned)(q8(v.w) & 255) << 24);
}

// ---------------- prep: quantize x/w to i8, norms, gb. One wave per row. ----------------
__global__ __launch_bounds__(256) void prep_k(const float* __restrict__ x, const float* __restrict__ w,
                                              const float* __restrict__ rel,
                                              signed char* __restrict__ xq, signed char* __restrict__ wq,
                                              float* __restrict__ x2p, float* __restrict__ w2p,
                                              float* __restrict__ rsump, float* __restrict__ gbp) {
    const int lane = threadIdx.x & 63, wave = threadIdx.x >> 6;
    const int row = (blockIdx.x << 2) + wave;
    if (row < B_DIM) {
        const float4* xr = (const float4*)(x + (size_t)row * D_DIM);
        unsigned* xqr = (unsigned*)(xq + (size_t)row * D_DIM);
        float ss = 0.f;
#pragma unroll
        for (int j = 0; j < 4; ++j) {
            const float4 v = xr[lane + j * 64];
            ss += v.x * v.x + v.y * v.y + v.z * v.z + v.w * v.w;
            xqr[lane + j * 64] = pack4(v);
        }
#pragma unroll
        for (int o = 32; o; o >>= 1) ss += __shfl_xor(ss, o);
        if (lane == 0) x2p[row] = ss;
    } else {
        const int n = row - B_DIM;
        const float4* wr = (const float4*)(w + (size_t)n * D_DIM);
        const float4* rr = (const float4*)(rel + (size_t)n * D_DIM);
        unsigned* wqr = (unsigned*)(wq + (size_t)n * D_DIM);
        float ss = 0.f, rs = 0.f;
#pragma unroll
        for (int j = 0; j < 4; ++j) {
            const float4 v = wr[lane + j * 64];
            const float4 rv = rr[lane + j * 64];
            ss += v.x * v.x + v.y * v.y + v.z * v.z + v.w * v.w;
            rs += rv.x + rv.y + rv.z + rv.w;
            wqr[lane + j * 64] = pack4(v);
        }
#pragma unroll
        for (int o = 32; o; o >>= 1) { ss += __shfl_xor(ss, o); rs += __shfl_xor(rs, o); }
        if (lane == 0) {
            w2p[n] = ss;
            rsump[n] = rs;
            gbp[n] = ss + (1e-7f * (float)D_DIM) / rs;
        }
    }
}

// ---------------- i8 GEMM -> per-64col tile min (f32) + 4-bit residuals ----------------
// 256x128 block tile, BK=64, 4 waves (2m x 2n), wave tile 128x64 (8x4 of 16x16x64 MFMA).
// 48KB LDS dbuf -> 3 blocks/CU. Grid 1024 with 2D-slab XCD swizzle (4MB L2 working set).
__global__ __launch_bounds__(256, 3) void gemm_k(const signed char* __restrict__ xq,
                                                 const signed char* __restrict__ wq,
                                                 const float* __restrict__ gbp,
                                                 unsigned short* __restrict__ resq,
                                                 float* __restrict__ tminp) {
    __shared__ char smem[49152];   // [2 buf][A 16KB | B 8KB]
    const int t = threadIdx.x;
    // 2D slab XCD swizzle: region = bid%8 (one per XCD), region covers 8 mt x 16 nt.
    // Per-XCD L2 working set: A 8x256KB + B 16x128KB = 4MB.
    const int region = blockIdx.x & 7;
    const int local  = blockIdx.x >> 3;            // 0..127
    const int mt = ((region >> 1) << 3) + (local >> 4);   // 0..31
    const int nt = ((region & 1) << 4) + (local & 15);    // 0..31
    const int m0 = mt * 256, n0 = nt * 128;
    const int lane = t & 63, wave = t >> 6;
    const int q = lane >> 4, ln = lane & 15;
    const int wm = wave >> 1, wn = wave & 1;       // 2 x 2 wave grid

    intv4 acc[8][4];
#pragma unroll
    for (int i = 0; i < 8; ++i)
#pragma unroll
        for (int j = 0; j < 4; ++j) acc[i][j] = (intv4){0, 0, 0, 0};

    // staging: linear LDS dest (slot S), inverse-swizzled global source.
    // slot S -> row = S>>2, cslot = S&3; global chunk = cslot ^ (row&3).
    int gA[4], gB[2];
#pragma unroll
    for (int s = 0; s < 4; ++s) {
        const int S = t + s * 256, r = S >> 2;
        gA[s] = r * D_DIM + (((S & 3) ^ (r & 3)) * 16);
    }
#pragma unroll
    for (int s = 0; s < 2; ++s) {
        const int S = t + s * 256, r = S >> 2;
        gB[s] = r * D_DIM + (((S & 3) ^ (r & 3)) * 16);
    }
    const signed char* Ap = xq + (size_t)m0 * D_DIM;
    const signed char* Bp = wq + (size_t)n0 * D_DIM;

    // ds_read: row = (wm*128|wn*64) + i*16 + ln -> row&3 == ln&3; chunk slot = q^(ln&3).
    const int cslot = (q ^ (ln & 3)) * 16;
    const int aBase = (wm * 128 + ln) * 64;
    const int bBase = (wn * 64 + ln) * 64;

#define STG(kt_, buf_) do {                                                          \
        char* base_ = smem + (buf_) * 24576;                                         \
        const int k0_ = (kt_) * 64;                                                  \
        _Pragma("unroll")                                                            \
        for (int s_ = 0; s_ < 4; ++s_)                                               \
            async16(base_ + (t + s_ * 256) * 16, Ap + gA[s_] + k0_);                 \
        _Pragma("unroll")                                                            \
        for (int s_ = 0; s_ < 2; ++s_)                                               \
            async16(base_ + 16384 + (t + s_ * 256) * 16, Bp + gB[s_] + k0_);         \
    } while (0)

    STG(0, 0);
#pragma unroll 4
    for (int kt = 0; kt < 16; ++kt) {
        if (kt < 15) {
            STG(kt + 1, (kt + 1) & 1);   // writes other buffer; WAR-safe (prev end-barrier)
            asm volatile("s_waitcnt vmcnt(6)" ::: "memory");   // kt's 6 landed, kt+1's in flight
        } else {
            asm volatile("s_waitcnt vmcnt(0)" ::: "memory");
        }
        __builtin_amdgcn_s_barrier();
        const char* sa = smem + (kt & 1) * 24576;
        const char* sb = sa + 16384;
        intv4 a[8], b[4];
#pragma unroll
        for (int i = 0; i < 8; ++i) a[i] = *(const intv4*)(sa + aBase + i * 1024 + cslot);
#pragma unroll
        for (int j = 0; j < 4; ++j) b[j] = *(const intv4*)(sb + bBase + j * 1024 + cslot);
        __builtin_amdgcn_s_setprio(1);
#pragma unroll
        for (int i = 0; i < 8; ++i)
#pragma unroll
            for (int j = 0; j < 4; ++j)
                acc[i][j] = __builtin_amdgcn_mfma_i32_16x16x64_i8(a[i], b[j], acc[i][j], 0, 0, 0);
        __builtin_amdgcn_s_setprio(0);
        asm volatile("" ::: "memory");
        __builtin_amdgcn_s_barrier();
    }
#undef STG

    // epilogue: g = gb[n] - 2*s/QS^2; per-(row, 64-tile) f32 min + 4-bit residual (step 1.0)
    // Each wave owns ONE 64-col tile: tile64 = nt*2 + wn.
    float gbv[4];
#pragma unroll
    for (int j = 0; j < 4; ++j) gbv[j] = gbp[n0 + wn * 64 + j * 16 + ln];
    const float cf = 2.0f * INV_QS2;
    const int tile64 = nt * 2 + wn;
#pragma unroll
    for (int i = 0; i < 8; ++i) {
#pragma unroll
        for (int r = 0; r < 4; ++r) {
            const int m = m0 + wm * 128 + i * 16 + q * 4 + r;
            float g[4];
            float mn = 3.4e38f;
#pragma unroll
            for (int j = 0; j < 4; ++j) {
                g[j] = gbv[j] - cf * (float)acc[i][j][r];
                mn = fminf(mn, g[j]);
            }
#pragma unroll
            for (int o = 1; o < 16; o <<= 1) mn = fminf(mn, __shfl_xor(mn, o));
            if (ln == 0) tminp[(size_t)m * 64 + tile64] = mn;
            unsigned u = 0;
#pragma unroll
            for (int j = 0; j < 4; ++j) {
                int a4 = (int)rintf(g[j] - mn);
                a4 = (a4 > 15) ? 15 : a4;
                u |= (unsigned)a4 << (4 * j);
            }
            resq[(size_t)m * 1024 + tile64 * 16 + ln] = (unsigned short)u;
        }
    }
}

// ---------------- resolve winner per row: tile-pruned; exact f32 re-rank only on ties ----------------
__global__ __launch_bounds__(256) void resolve_k(const unsigned short* __restrict__ resq,
                                                 const float* __restrict__ tminp,
                                                 const float* __restrict__ x2p,
                                                 const float* __restrict__ x, const float* __restrict__ w,
                                                 const float* __restrict__ w2p, const float* __restrict__ rsump,
                                                 const float* __restrict__ ncp,
                                                 int* __restrict__ win) {
    const int lane = threadIdx.x & 63, wave = threadIdx.x >> 6;
    const int b = (blockIdx.x << 2) + wave;
    const float tv = tminp[(size_t)b * 64 + lane];   // lane = 64-col tile index
    float rowmin = tv;
#pragma unroll
    for (int o = 32; o; o >>= 1) rowmin = fminf(rowmin, __shfl_xor(rowmin, o));
    const float th = rowmin + MARGIN_G;
    const float thq = th + 0.5f;                     // +0.5 nibble-quant slack
    const unsigned long long tmask = __ballot(tv <= th);
    const float x2v = x2p[b];
    const unsigned short* rrow = resq + (size_t)b * 1024;
    const int nibsh = (lane >> 4) * 4;

    int cnt = 0, myn = -1;
    float myg = 0.0f;
    unsigned long long tm = tmask;
    while (tm) {
        const int tt = __ffsll((long long)tm) - 1;
        tm &= tm - 1;
        const float tb = __shfl(tv, tt);
        const unsigned short pv = rrow[tt * 16 + (lane & 15)];
        const float g = tb + (float)((pv >> nibsh) & 15);
        const bool c = (g <= thq);
        cnt += __popcll(__ballot(c));
        if (c && myn < 0) { myn = tt * 64 + lane; myg = g; }
    }

    if (cnt == 1) {
        if (myn >= 0) {
            const float act = ncp[myn] * (float)D_DIM / ((float)D_DIM + x2v + myg);
            win[b] = (act >= ATc) ? myn : -1;
        }
    } else {
        // exact f32 re-rank of all candidates
        const float4* xr = (const float4*)(x + (size_t)b * D_DIM);
        float4 xv[4];
#pragma unroll
        for (int j = 0; j < 4; ++j) xv[j] = xr[lane + j * 64];
        float best_act = -1.0f;
        int best_n = N_DIM;
        tm = tmask;
        while (tm) {
            const int tt = __ffsll((long long)tm) - 1;
            tm &= tm - 1;
            const float tb = __shfl(tv, tt);
            const unsigned short pv = rrow[tt * 16 + (lane & 15)];
            const float g = tb + (float)((pv >> nibsh) & 15);
            unsigned long long cm = __ballot(g <= thq);
            while (cm) {
                const int l = __ffsll((long long)cm) - 1;
                cm &= cm - 1;
                const int n = tt * 64 + l;
                const float4* wr = (const float4*)(w + (size_t)n * D_DIM);
                float p = 0.f;
#pragma unroll
                for (int j = 0; j < 4; ++j) {
                    const float4 wv = wr[lane + j * 64];
                    p += xv[j].x * wv.x + xv[j].y * wv.y + xv[j].z * wv.z + xv[j].w * wv.w;
                }
#pragma unroll
                for (int o = 32; o; o >>= 1) p += __shfl_xor(p, o);
                const float dist = x2v + w2p[n] - 2.0f * p;
                const float rs = rsump[n];
                const float dw = dist * rs * (1.0f / (float)D_DIM);
                const float a = rs * ncp[n] / (rs + dw + 1e-7f);
                if (a > best_act || (a == best_act && n < best_n)) { best_act = a; best_n = n; }
            }
        }
        if (lane == 0) win[b] = (best_act >= ATc) ? best_n : -1;
    }
}

// ---------------- per-node gather + update + outputs ----------------
__global__ __launch_bounds__(256) void finalize_k(const float* __restrict__ x, const float* __restrict__ w,
                                                  const float* __restrict__ mavg, const int* __restrict__ win,
                                                  float* __restrict__ out) {
    const int n = blockIdx.x, t = threadIdx.x;
    __shared__ unsigned short list[B_DIM];
    __shared__ int cnt;
    __shared__ float smax[4], smin[4], ssum[4];
    if (t == 0) cnt = 0;
    __syncthreads();
    const int4* wp = (const int4*)win;
#pragma unroll
    for (int k = 0; k < 8; ++k) {
        const int4 v = wp[k * 256 + t];
        const int b0 = (k * 256 + t) * 4;
        if (v.x == n) list[atomicAdd(&cnt, 1)] = (unsigned short)(b0 + 0);
        if (v.y == n) list[atomicAdd(&cnt, 1)] = (unsigned short)(b0 + 1);
        if (v.z == n) list[atomicAdd(&cnt, 1)] = (unsigned short)(b0 + 2);
        if (v.w == n) list[atomicAdd(&cnt, 1)] = (unsigned short)(b0 + 3);
    }
    __syncthreads();
    const int c = cnt;
    float4 s = {0.f, 0.f, 0.f, 0.f};
    for (int e = 0; e < c; ++e) {
        const float4 xv = ((const float4*)(x + (size_t)list[e] * D_DIM))[t];
        s.x += xv.x; s.y += xv.y; s.z += xv.z; s.w += xv.w;
    }
    const float has = (c > 0) ? 1.0f : 0.0f;
    const float invc = 1.0f / fmaxf((float)c, 1.0f);
    const size_t base4 = (size_t)n * (D_DIM / 4);
    const float4 wv = ((const float4*)w)[base4 + t];
    const float4 mk = ((const float4*)mavg)[base4 + t];
    float4 ms, mv;
    ms.x = s.x * invc; ms.y = s.y * invc; ms.z = s.z * invc; ms.w = s.w * invc;
    mv.x = EMAc * fabsf(ms.x - wv.x) + (1.0f - EMAc) * mk.x;
    mv.y = EMAc * fabsf(ms.y - wv.y) + (1.0f - EMAc) * mk.y;
    mv.z = EMAc * fabsf(ms.z - wv.z) + (1.0f - EMAc) * mk.z;
    mv.w = EMAc * fabsf(ms.w - wv.w) + (1.0f - EMAc) * mk.w;
    float lmax = fmaxf(fmaxf(mv.x, mv.y), fmaxf(mv.z, mv.w));
    float lmin = fminf(fminf(mv.x, mv.y), fminf(mv.z, mv.w));
    float lsum = mv.x + mv.y + mv.z + mv.w;
#pragma unroll
    for (int o = 32; o; o >>= 1) {
        lmax = fmaxf(lmax, __shfl_xor(lmax, o));
        lmin = fminf(lmin, __shfl_xor(lmin, o));
        lsum += __shfl_xor(lsum, o);
    }
    const int wave = t >> 6, lane = t & 63;
    if (lane == 0) { smax[wave] = lmax; smin[wave] = lmin; ssum[wave] = lsum; }
    __syncthreads();
    const float mx = fmaxf(fmaxf(smax[0], smax[1]), fmaxf(smax[2], smax[3]));
    const float mn = fminf(fminf(smin[0], smin[1]), fminf(smin[2], smin[3]));
    const float avg = (ssum[0] + ssum[1] + ssum[2] + ssum[3]) * (1.0f / (float)D_DIM);
    const float scale = 0.5f * (mx - mn);       // EPS_DS*(mx-mn)
    const float invs = (scale > 0.0f) ? 1.0f / scale : 0.0f;
    float4 relv;
    if (scale > 0.0f) {
        relv.x = 1.0f / (1.0f + __expf((mv.x - avg) * invs));
        relv.y = 1.0f / (1.0f + __expf((mv.y - avg) * invs));
        relv.z = 1.0f / (1.0f + __expf((mv.z - avg) * invs));
        relv.w = 1.0f / (1.0f + __expf((mv.w - avg) * invs));
    } else {
        relv.x = relv.y = relv.z = relv.w = 1.0f;
    }
    float4* o0 = (float4*)out;
    float4 r0, r1, r2;
    r0.x = ms.x * has; r0.y = ms.y * has; r0.z = ms.z * has; r0.w = ms.w * has;
    r1.x = (wv.x + LRc * (ms.x - wv.x)) * has;
    r1.y = (wv.y + LRc * (ms.y - wv.y)) * has;
    r1.z = (wv.z + LRc * (ms.z - wv.z)) * has;
    r1.w = (wv.w + LRc * (ms.w - wv.w)) * has;
    r2.x = relv.x * has; r2.y = relv.y * has; r2.z = relv.z * has; r2.w = relv.w * has;
    o0[base4 + t] = r0;
    o0[ND / 4 + base4 + t] = r1;
    o0[2 * (ND / 4) + base4 + t] = r2;
}

extern "C" void kernel_launch(void* const* d_in, const int* in_sizes, int n_in,
                              void* d_out, int out_size, void* d_ws, size_t ws_size,
                              hipStream_t stream) {
    const float* x    = (const float*)d_in[0];
    const float* w    = (const float*)d_in[1];
    const float* rel  = (const float*)d_in[2];
    const float* mavg = (const float*)d_in[3];
    const float* nc   = (const float*)d_in[4];
    float* out = (float*)d_out;

    char* p = (char*)d_ws;
    size_t off = 0;
    auto take = [&](size_t bytes) -> char* {
        char* r = p + off;
        off += (bytes + 255) & ~(size_t)255;
        return r;
    };
    signed char* xq = (signed char*)take((size_t)B_DIM * D_DIM);
    signed char* wq = (signed char*)take((size_t)N_DIM * D_DIM);
    float* x2       = (float*)take((size_t)B_DIM * 4);
    float* w2       = (float*)take((size_t)N_DIM * 4);
    float* rsum     = (float*)take((size_t)N_DIM * 4);
    float* gb       = (float*)take((size_t)N_DIM * 4);
    unsigned short* resq = (unsigned short*)take((size_t)B_DIM * 1024 * 2);  // 4-bit/node
    float* tminp    = (float*)take((size_t)B_DIM * 64 * 4);
    int* win        = (int*)take((size_t)B_DIM * 4);

    prep_k<<<(B_DIM + N_DIM) / 4, 256, 0, stream>>>(x, w, rel, xq, wq, x2, w2, rsum, gb);
    gemm_k<<<1024, 256, 0, stream>>>(xq, wq, gb, resq, tminp);
    resolve_k<<<B_DIM / 4, 256, 0, stream>>>(resq, tminp, x2, x, w, w2, rsum, nc, win);
    finalize_k<<<N_DIM, 256, 0, stream>>>(x, w, mavg, win, out);
}

// Round 4
// 207.870 us; speedup vs baseline: 1.4173x; 1.4173x over previous
//
#include <hip/hip_runtime.h>
#include <stdint.h>

// R14: byte-exact revert to R10 (proven 203.9us; R11/R12 schedule variants neutral,
// R13 tile/swizzle change regressed) + ONE variable: XCD-quadrant block mapping.
// Diagnosis: R10/R11/R12 all pinned at 46-48us (37% of i8 peak) regardless of K-loop
// schedule; FETCH 22.6MB vs 12.3MB compulsory. Per-XCD resident working set under the
// old mt=bid&63 mapping was ~4MB (12 B-panels + 8 A-panels) = exactly L2 capacity ->
// borderline thrash -> staging served from IF$ at ~25-35us serial supply = the wall.
// New mapping: xcd=bid&7 owns an exclusive 8-mt slab; its 128 blocks run as 2 temporal
// quadrants of 8 nt each -> working set 8x128KB(A) + 8x256KB(B) = 3MB < 4MB L2.
// BN=256 kept -> resq/tminp 128B-line ownership unchanged (no write amplification).
// Everything else identical to R10.

#define B_DIM 8192
#define D_DIM 1024
#define N_DIM 4096
#define ND ((size_t)N_DIM * D_DIM)
#define LRc 0.02f
#define ATc 0.3f
#define EMAc (0.02f * 0.1f)   // LR*DSBETA = 0.002
#define QS 32.0f              // i8 quant scale
#define INV_QS2 (1.0f / (QS * QS))
#define MARGIN_G 10.0f        // candidate window in g-units (~9 sigma of i8 error; +0.5 nib slack in test)

typedef int intv4 __attribute__((ext_vector_type(4)));

__device__ __forceinline__ void async16(void* lds, const void* g) {
    __builtin_amdgcn_global_load_lds((const __attribute__((address_space(1))) void*)g,
                                     (__attribute__((address_space(3))) void*)lds, 16, 0, 0);
}

__device__ __forceinline__ int q8(float v) {
    return (int)rintf(fminf(fmaxf(v * QS, -127.0f), 127.0f));
}

__device__ __forceinline__ unsigned pack4(float4 v) {
    return (unsigned)(q8(v.x) & 255) | ((unsigned)(q8(v.y) & 255) << 8)
         | ((unsigned)(q8(v.z) & 255) << 16) | ((unsigned)(q8(v.w) & 255) << 24);
}

// ---------------- prep: quantize x/w to i8, norms, gb. One wave per row. ----------------
__global__ __launch_bounds__(256) void prep_k(const float* __restrict__ x, const float* __restrict__ w,
                                              const float* __restrict__ rel,
                                              signed char* __restrict__ xq, signed char* __restrict__ wq,
                                              float* __restrict__ x2p, float* __restrict__ w2p,
                                              float* __restrict__ rsump, float* __restrict__ gbp) {
    const int lane = threadIdx.x & 63, wave = threadIdx.x >> 6;
    const int row = (blockIdx.x << 2) + wave;
    if (row < B_DIM) {
        const float4* xr = (const float4*)(x + (size_t)row * D_DIM);
        unsigned* xqr = (unsigned*)(xq + (size_t)row * D_DIM);
        float ss = 0.f;
#pragma unroll
        for (int j = 0; j < 4; ++j) {
            const float4 v = xr[lane + j * 64];
            ss += v.x * v.x + v.y * v.y + v.z * v.z + v.w * v.w;
            xqr[lane + j * 64] = pack4(v);
        }
#pragma unroll
        for (int o = 32; o; o >>= 1) ss += __shfl_xor(ss, o);
        if (lane == 0) x2p[row] = ss;
    } else {
        const int n = row - B_DIM;
        const float4* wr = (const float4*)(w + (size_t)n * D_DIM);
        const float4* rr = (const float4*)(rel + (size_t)n * D_DIM);
        unsigned* wqr = (unsigned*)(wq + (size_t)n * D_DIM);
        float ss = 0.f, rs = 0.f;
#pragma unroll
        for (int j = 0; j < 4; ++j) {
            const float4 v = wr[lane + j * 64];
            const float4 rv = rr[lane + j * 64];
            ss += v.x * v.x + v.y * v.y + v.z * v.z + v.w * v.w;
            rs += rv.x + rv.y + rv.z + rv.w;
            wqr[lane + j * 64] = pack4(v);
        }
#pragma unroll
        for (int o = 32; o; o >>= 1) { ss += __shfl_xor(ss, o); rs += __shfl_xor(rs, o); }
        if (lane == 0) {
            w2p[n] = ss;
            rsump[n] = rs;
            // act = nc*D/(D + x2 + g), g = w2 - 2s + D*1e-7/rs -> rank by min g
            gbp[n] = ss + (1e-7f * (float)D_DIM) / rs;
        }
    }
}

// ---------------- i8 GEMM -> per-64col tile min (f32) + 4-bit residuals ----------------
// 128x256 block tile, BK=128, 4 waves each own a 64x128 quadrant (4x8 of 16x16x64 MFMA).
__global__ __launch_bounds__(256, 2) void gemm_k(const signed char* __restrict__ xq,
                                                 const signed char* __restrict__ wq,
                                                 const float* __restrict__ gbp,
                                                 unsigned short* __restrict__ resq,
                                                 float* __restrict__ tminp) {
    __shared__ int4 As[1024];   // 128 rows x 128 B
    __shared__ int4 Bs[2048];   // 256 rows x 128 B
    const int t = threadIdx.x;
    // R14 change (ONLY change vs R10): XCD-quadrant mapping.
    // xcd = bid&7 (dispatch round-robins XCDs); each XCD owns mt in [xcd*8, xcd*8+8)
    // exclusively and walks nt in two temporal quadrants of 8.
    // Per-XCD L2 working set: A 8x128KB + B 8x256KB = 3MB < 4MB.
    const int xcd  = blockIdx.x & 7;
    const int idx  = blockIdx.x >> 3;        // 0..127
    const int quad = idx >> 6;               // 0..1
    const int wi   = idx & 63;               // 0..63
    const int mt = xcd * 8 + (wi >> 3);      // 0..63 (64 m-tiles, B/128)
    const int nt = quad * 8 + (wi & 7);      // 0..15 (16 n-tiles, N/256)
    const int m0 = mt * 128, n0 = nt * 256;
    const int lane = t & 63, wave = t >> 6;
    const int q = lane >> 4, ln = lane & 15;
    const int wm = wave >> 1, wn = wave & 1;

    intv4 acc[4][8];
#pragma unroll
    for (int i = 0; i < 4; ++i)
#pragma unroll
        for (int j = 0; j < 8; ++j) acc[i][j] = (intv4){0, 0, 0, 0};

    // staging swizzle: slot L holds global (row r=L>>3, chunk c=(L&7)^(r&7)); read pos jx=k^(r&7)
    int rrA[4], jjA[4], rrB[8], jjB[8];
#pragma unroll
    for (int s = 0; s < 4; ++s) {
        int L = t + s * 256;
        rrA[s] = L >> 3; jjA[s] = (L & 7) ^ (rrA[s] & 7);
    }
#pragma unroll
    for (int s = 0; s < 8; ++s) {
        int L = t + s * 256;
        rrB[s] = L >> 3; jjB[s] = (L & 7) ^ (rrB[s] & 7);
    }

    const signed char* Ap = xq + (size_t)m0 * D_DIM;
    const signed char* Bp = wq + (size_t)n0 * D_DIM;
    for (int kt = 0; kt < 8; ++kt) {
        const int k0 = kt * 128;
#pragma unroll
        for (int s = 0; s < 4; ++s)
            async16((char*)As + (t + s * 256) * 16, Ap + (size_t)rrA[s] * D_DIM + k0 + jjA[s] * 16);
#pragma unroll
        for (int s = 0; s < 8; ++s)
            async16((char*)Bs + (t + s * 256) * 16, Bp + (size_t)rrB[s] * D_DIM + k0 + jjB[s] * 16);
        __syncthreads();
#pragma unroll
        for (int ks = 0; ks < 2; ++ks) {
            intv4 a[4], b[8];
#pragma unroll
            for (int i = 0; i < 4; ++i) {
                int r = wm * 64 + i * 16 + ln;
                int jx = (ks * 4 + q) ^ (r & 7);
                a[i] = *(const intv4*)((const char*)As + (r * 8 + jx) * 16);
            }
#pragma unroll
            for (int j = 0; j < 8; ++j) {
                int r = wn * 128 + j * 16 + ln;
                int jx = (ks * 4 + q) ^ (r & 7);
                b[j] = *(const intv4*)((const char*)Bs + (r * 8 + jx) * 16);
            }
#pragma unroll
            for (int i = 0; i < 4; ++i)
#pragma unroll
                for (int j = 0; j < 8; ++j)
                    acc[i][j] = __builtin_amdgcn_mfma_i32_16x16x64_i8(a[i], b[j], acc[i][j], 0, 0, 0);
        }
        __syncthreads();
    }

    // epilogue: g = gb[n] - 2*s/QS^2; per-(row, 64-tile) f32 min + 4-bit residual (step 1.0)
    // resq layout: u16 slot = tile64*16 + (n&15), nibble = (n>>4)&3; 1024 u16 per row.
    float gbv[8];
#pragma unroll
    for (int j = 0; j < 8; ++j) gbv[j] = gbp[n0 + wn * 128 + j * 16 + ln];
    const float cf = 2.0f * INV_QS2;
    const int tileA = nt * 4 + wn * 2;        // 64-col tile indices this wave covers
#pragma unroll
    for (int i = 0; i < 4; ++i) {
#pragma unroll
        for (int r = 0; r < 4; ++r) {
            const int m = m0 + wm * 64 + i * 16 + q * 4 + r;
            float g[8];
            float mnA = 3.4e38f, mnB = 3.4e38f;
#pragma unroll
            for (int j = 0; j < 8; ++j) {
                g[j] = gbv[j] - cf * (float)acc[i][j][r];
                if (j < 4) mnA = fminf(mnA, g[j]); else mnB = fminf(mnB, g[j]);
            }
#pragma unroll
            for (int o = 1; o < 16; o <<= 1) {
                mnA = fminf(mnA, __shfl_xor(mnA, o));
                mnB = fminf(mnB, __shfl_xor(mnB, o));
            }
            if (ln == 0) {
                tminp[(size_t)m * 64 + tileA + 0] = mnA;
                tminp[(size_t)m * 64 + tileA + 1] = mnB;
            }
            unsigned uA = 0, uB = 0;
#pragma unroll
            for (int j = 0; j < 4; ++j) {
                int a4 = (int)rintf(g[j] - mnA);
                a4 = (a4 > 15) ? 15 : a4;
                uA |= (unsigned)a4 << (4 * j);
                int b4 = (int)rintf(g[j + 4] - mnB);
                b4 = (b4 > 15) ? 15 : b4;
                uB |= (unsigned)b4 << (4 * j);
            }
            unsigned short* rq = resq + (size_t)m * 1024;
            rq[(tileA + 0) * 16 + ln] = (unsigned short)uA;
            rq[(tileA + 1) * 16 + ln] = (unsigned short)uB;
        }
    }
}

// ---------------- resolve winner per row: tile-pruned; exact f32 re-rank only on ties ----------------
__global__ __launch_bounds__(256) void resolve_k(const unsigned short* __restrict__ resq,
                                                 const float* __restrict__ tminp,
                                                 const float* __restrict__ x2p,
                                                 const float* __restrict__ x, const float* __restrict__ w,
                                                 const float* __restrict__ w2p, const float* __restrict__ rsump,
                                                 const float* __restrict__ ncp,
                                                 int* __restrict__ win) {
    const int lane = threadIdx.x & 63, wave = threadIdx.x >> 6;
    const int b = (blockIdx.x << 2) + wave;
    const float tv = tminp[(size_t)b * 64 + lane];   // lane = 64-col tile index
    float rowmin = tv;
#pragma unroll
    for (int o = 32; o; o >>= 1) rowmin = fminf(rowmin, __shfl_xor(rowmin, o));
    const float th = rowmin + MARGIN_G;
    const float thq = th + 0.5f;                     // +0.5 nibble-quant slack
    const unsigned long long tmask = __ballot(tv <= th);
    const float x2v = x2p[b];
    const unsigned short* rrow = resq + (size_t)b * 1024;
    const int nibsh = (lane >> 4) * 4;

    int cnt = 0, myn = -1;
    float myg = 0.0f;
    unsigned long long tm = tmask;
    while (tm) {
        const int tt = __ffsll((long long)tm) - 1;
        tm &= tm - 1;
        const float tb = __shfl(tv, tt);
        const unsigned short pv = rrow[tt * 16 + (lane & 15)];
        const float g = tb + (float)((pv >> nibsh) & 15);
        const bool c = (g <= thq);
        cnt += __popcll(__ballot(c));
        if (c && myn < 0) { myn = tt * 64 + lane; myg = g; }
    }

    if (cnt == 1) {
        if (myn >= 0) {
            const float act = ncp[myn] * (float)D_DIM / ((float)D_DIM + x2v + myg);
            win[b] = (act >= ATc) ? myn : -1;
        }
    } else {
        // exact f32 re-rank of all candidates
        const float4* xr = (const float4*)(x + (size_t)b * D_DIM);
        float4 xv[4];
#pragma unroll
        for (int j = 0; j < 4; ++j) xv[j] = xr[lane + j * 64];
        float best_act = -1.0f;
        int best_n = N_DIM;
        tm = tmask;
        while (tm) {
            const int tt = __ffsll((long long)tm) - 1;
            tm &= tm - 1;
            const float tb = __shfl(tv, tt);
            const unsigned short pv = rrow[tt * 16 + (lane & 15)];
            const float g = tb + (float)((pv >> nibsh) & 15);
            unsigned long long cm = __ballot(g <= thq);
            while (cm) {
                const int l = __ffsll((long long)cm) - 1;
                cm &= cm - 1;
                const int n = tt * 64 + l;
                const float4* wr = (const float4*)(w + (size_t)n * D_DIM);
                float p = 0.f;
#pragma unroll
                for (int j = 0; j < 4; ++j) {
                    const float4 wv = wr[lane + j * 64];
                    p += xv[j].x * wv.x + xv[j].y * wv.y + xv[j].z * wv.z + xv[j].w * wv.w;
                }
#pragma unroll
                for (int o = 32; o; o >>= 1) p += __shfl_xor(p, o);
                const float dist = x2v + w2p[n] - 2.0f * p;
                const float rs = rsump[n];
                const float dw = dist * rs * (1.0f / (float)D_DIM);
                const float a = rs * ncp[n] / (rs + dw + 1e-7f);
                if (a > best_act || (a == best_act && n < best_n)) { best_act = a; best_n = n; }
            }
        }
        if (lane == 0) win[b] = (best_act >= ATc) ? best_n : -1;
    }
}

// ---------------- per-node gather + update + outputs ----------------
__global__ __launch_bounds__(256) void finalize_k(const float* __restrict__ x, const float* __restrict__ w,
                                                  const float* __restrict__ mavg, const int* __restrict__ win,
                                                  float* __restrict__ out) {
    const int n = blockIdx.x, t = threadIdx.x;
    __shared__ unsigned short list[B_DIM];
    __shared__ int cnt;
    __shared__ float smax[4], smin[4], ssum[4];
    if (t == 0) cnt = 0;
    __syncthreads();
    const int4* wp = (const int4*)win;
#pragma unroll
    for (int k = 0; k < 8; ++k) {
        const int4 v = wp[k * 256 + t];
        const int b0 = (k * 256 + t) * 4;
        if (v.x == n) list[atomicAdd(&cnt, 1)] = (unsigned short)(b0 + 0);
        if (v.y == n) list[atomicAdd(&cnt, 1)] = (unsigned short)(b0 + 1);
        if (v.z == n) list[atomicAdd(&cnt, 1)] = (unsigned short)(b0 + 2);
        if (v.w == n) list[atomicAdd(&cnt, 1)] = (unsigned short)(b0 + 3);
    }
    __syncthreads();
    const int c = cnt;
    float4 s = {0.f, 0.f, 0.f, 0.f};
    for (int e = 0; e < c; ++e) {
        const float4 xv = ((const float4*)(x + (size_t)list[e] * D_DIM))[t];
        s.x += xv.x; s.y += xv.y; s.z += xv.z; s.w += xv.w;
    }
    const float has = (c > 0) ? 1.0f : 0.0f;
    const float invc = 1.0f / fmaxf((float)c, 1.0f);
    const size_t base4 = (size_t)n * (D_DIM / 4);
    const float4 wv = ((const float4*)w)[base4 + t];
    const float4 mk = ((const float4*)mavg)[base4 + t];
    float4 ms, mv;
    ms.x = s.x * invc; ms.y = s.y * invc; ms.z = s.z * invc; ms.w = s.w * invc;
    mv.x = EMAc * fabsf(ms.x - wv.x) + (1.0f - EMAc) * mk.x;
    mv.y = EMAc * fabsf(ms.y - wv.y) + (1.0f - EMAc) * mk.y;
    mv.z = EMAc * fabsf(ms.z - wv.z) + (1.0f - EMAc) * mk.z;
    mv.w = EMAc * fabsf(ms.w - wv.w) + (1.0f - EMAc) * mk.w;
    float lmax = fmaxf(fmaxf(mv.x, mv.y), fmaxf(mv.z, mv.w));
    float lmin = fminf(fminf(mv.x, mv.y), fminf(mv.z, mv.w));
    float lsum = mv.x + mv.y + mv.z + mv.w;
#pragma unroll
    for (int o = 32; o; o >>= 1) {
        lmax = fmaxf(lmax, __shfl_xor(lmax, o));
        lmin = fminf(lmin, __shfl_xor(lmin, o));
        lsum += __shfl_xor(lsum, o);
    }
    const int wave = t >> 6, lane = t & 63;
    if (lane == 0) { smax[wave] = lmax; smin[wave] = lmin; ssum[wave] = lsum; }
    __syncthreads();
    const float mx = fmaxf(fmaxf(smax[0], smax[1]), fmaxf(smax[2], smax[3]));
    const float mn = fminf(fminf(smin[0], smin[1]), fminf(smin[2], smin[3]));
    const float avg = (ssum[0] + ssum[1] + ssum[2] + ssum[3]) * (1.0f / (float)D_DIM);
    const float scale = 0.5f * (mx - mn);       // EPS_DS*(mx-mn)
    const float invs = (scale > 0.0f) ? 1.0f / scale : 0.0f;
    float4 relv;
    if (scale > 0.0f) {
        relv.x = 1.0f / (1.0f + __expf((mv.x - avg) * invs));
        relv.y = 1.0f / (1.0f + __expf((mv.y - avg) * invs));
        relv.z = 1.0f / (1.0f + __expf((mv.z - avg) * invs));
        relv.w = 1.0f / (1.0f + __expf((mv.w - avg) * invs));
    } else {
        relv.x = relv.y = relv.z = relv.w = 1.0f;
    }
    float4* o0 = (float4*)out;
    float4 r0, r1, r2;
    r0.x = ms.x * has; r0.y = ms.y * has; r0.z = ms.z * has; r0.w = ms.w * has;
    r1.x = (wv.x + LRc * (ms.x - wv.x)) * has;
    r1.y = (wv.y + LRc * (ms.y - wv.y)) * has;
    r1.z = (wv.z + LRc * (ms.z - wv.z)) * has;
    r1.w = (wv.w + LRc * (ms.w - wv.w)) * has;
    r2.x = relv.x * has; r2.y = relv.y * has; r2.z = relv.z * has; r2.w = relv.w * has;
    o0[base4 + t] = r0;
    o0[ND / 4 + base4 + t] = r1;
    o0[2 * (ND / 4) + base4 + t] = r2;
}

extern "C" void kernel_launch(void* const* d_in, const int* in_sizes, int n_in,
                              void* d_out, int out_size, void* d_ws, size_t ws_size,
                              hipStream_t stream) {
    const float* x    = (const float*)d_in[0];
    const float* w    = (const float*)d_in[1];
    const float* rel  = (const float*)d_in[2];
    const float* mavg = (const float*)d_in[3];
    const float* nc   = (const float*)d_in[4];
    float* out = (float*)d_out;

    char* p = (char*)d_ws;
    size_t off = 0;
    auto take = [&](size_t bytes) -> char* {
        char* r = p + off;
        off += (bytes + 255) & ~(size_t)255;
        return r;
    };
    signed char* xq = (signed char*)take((size_t)B_DIM * D_DIM);
    signed char* wq = (signed char*)take((size_t)N_DIM * D_DIM);
    float* x2       = (float*)take((size_t)B_DIM * 4);
    float* w2       = (float*)take((size_t)N_DIM * 4);
    float* rsum     = (float*)take((size_t)N_DIM * 4);
    float* gb       = (float*)take((size_t)N_DIM * 4);
    unsigned short* resq = (unsigned short*)take((size_t)B_DIM * 1024 * 2);  // 4-bit/node
    float* tminp    = (float*)take((size_t)B_DIM * 64 * 4);
    int* win        = (int*)take((size_t)B_DIM * 4);

    prep_k<<<(B_DIM + N_DIM) / 4, 256, 0, stream>>>(x, w, rel, xq, wq, x2, w2, rsum, gb);
    gemm_k<<<1024, 256, 0, stream>>>(xq, wq, gb, resq, tminp);
    resolve_k<<<B_DIM / 4, 256, 0, stream>>>(resq, tminp, x2, x, w, w2, rsum, nc, win);
    finalize_k<<<N_DIM, 256, 0, stream>>>(x, w, mavg, win, out);
}